// Round 7
// baseline (242.014 us; speedup 1.0000x reference)
//
#include <hip/hip_runtime.h>
#include <math.h>

#define NB 2
#define NC 96
#define NN 8000
#define DI 192
#define DS 16
#define DTRK 6
#define KCH 160
#define LCH 50

// ws layout (element offsets, 4B each)
#define OFF_KEYS 0
#define OFF_RANK 8000
#define OFF_AEXP 24000
#define OFF_XC   32768                        // (B,N,DI) — reused as Y after scan
#define OFF_Z    (OFF_XC  + NB*NN*DI)
#define OFF_XCV  (OFF_Z   + NB*NN*DI)
#define OFF_DT   (OFF_XCV + NB*NN*DI)         // reused as YP (B,N,96) after scan3
#define OFF_BM   (OFF_DT  + NB*NN*DI)
#define OFF_CM   (OFF_BM  + NB*NN*DS)
#define OFF_CA   (OFF_CM  + NB*NN*DS)         // xn (B,N,96) aliases ca+cb (pre-scan); hs aliases ca
#define OFF_CB   (OFF_CA  + NB*KCH*DI*DS)

// ---------------- A1: projection keys + A = -exp(A_log) ----------------
__global__ void k_keys(const float* __restrict__ pv, const float* __restrict__ alog,
                       float* __restrict__ keys, float* __restrict__ aexp) {
    int t = blockIdx.x * 256 + threadIdx.x;
    if (t < NN) {
        int z = t / 400, rem = t % 400, y = rem / 20, x = rem % 20;
        keys[t] = (float)z * pv[0] + (float)y * pv[1] + (float)x * pv[2];
    } else if (t < NN + DI * DS) {
        int i = t - NN;
        aexp[i] = -expf(alog[i]);
    }
}

// ---------------- A2: O(N^2) stable rank (tie-break on index) ----------------
__global__ void k_rank(const float* __restrict__ keys, int* __restrict__ rank) {
    __shared__ float kj[250];
    int t = threadIdx.x;
    int j0 = blockIdx.y * 250;
    if (t < 250) kj[t] = keys[j0 + t];
    __syncthreads();
    int i = blockIdx.x * 256 + t;
    if (i >= NN) return;
    float ki = keys[i];
    int cnt = 0;
    #pragma unroll 5
    for (int j = 0; j < 250; ++j) {
        float kv = kj[j];
        int jj = j0 + j;
        cnt += (kv < ki || (kv == ki && jj < i)) ? 1 : 0;
    }
    atomicAdd(rank + i, cnt);
}

// ------- B1: LayerNorm + row-scatter to sorted xn (B,N,96) -------
__launch_bounds__(256)
__global__ void k_ln(const float* __restrict__ x, const float* __restrict__ nw,
                     const float* __restrict__ nbp, const int* __restrict__ rank,
                     float* __restrict__ xn) {
    __shared__ float xt[64][100];
    __shared__ int rk[64];
    __shared__ float nwb[NC], nbb[NC];
    int b = blockIdx.y, n0 = blockIdx.x * 64, t = threadIdx.x;
    int lane = t & 63, w = t >> 6;
    if (t < 64) rk[t] = rank[n0 + t];
    else if (t < 160) { int c = t - 64; nwb[c] = nw[c]; nbb[c] = nbp[c]; }
    for (int idx = t; idx < NC * 64; idx += 256) {
        int c = idx >> 6, p = idx & 63;
        xt[p][c] = x[((size_t)b * NC + c) * NN + n0 + p];
    }
    __syncthreads();
    // per-lane LN (4 waves redundant)
    float xr[96];
    float s = 0.f, sq = 0.f;
    #pragma unroll
    for (int c4 = 0; c4 < 24; ++c4) {
        float4 v = *(const float4*)&xt[lane][c4 * 4];
        xr[c4*4+0] = v.x; xr[c4*4+1] = v.y; xr[c4*4+2] = v.z; xr[c4*4+3] = v.w;
        s += v.x + v.y + v.z + v.w;
        sq += v.x*v.x + v.y*v.y + v.z*v.z + v.w*v.w;
    }
    float mu = s * (1.f / 96.f);
    float var = sq * (1.f / 96.f) - mu * mu;
    float rs = rsqrtf(var + 1e-5f);
    #pragma unroll
    for (int c = 0; c < 96; ++c) xr[c] = (xr[c] - mu) * rs * nwb[c] + nbb[c];
    __syncthreads();
    if (w == 0) {
        #pragma unroll
        for (int c = 0; c < 96; ++c) xt[lane][c] = xr[c];
    }
    __syncthreads();
    for (int idx = t; idx < 64 * 24; idx += 256) {
        int p = idx / 24, c4 = idx % 24;
        *(float4*)&xn[((size_t)b * NN + rk[p]) * NC + c4 * 4] = *(const float4*)&xt[p][c4 * 4];
    }
}

// ------- B2: in_proj GEMM, W-tile staged in LDS, uniform broadcast reads -------
__launch_bounds__(256, 2)
__global__ void k_inproj(const float* __restrict__ xn, const float* __restrict__ win,
                         float* __restrict__ xcout, float* __restrict__ zout) {
    __shared__ float wsm[96 * 96];             // 36.9 KB: W rows [g*96, g*96+96)
    __shared__ float smem[64 * 104];           // union: xs[96][65] then st[64][104]
    float (*xs)[65]  = (float(*)[65])smem;
    float (*st)[104] = (float(*)[104])smem;
    int b = blockIdx.z, g = blockIdx.y, n0 = blockIdx.x * 64, t = threadIdx.x;
    int lane = t & 63, w = t >> 6;

    const float4* wsrc = (const float4*)(win + (size_t)g * 96 * NC);
    for (int i = t; i < 96 * 96 / 4; i += 256) ((float4*)wsm)[i] = wsrc[i];
    for (int idx = t; idx < 64 * 96; idx += 256) {
        int p = idx / 96, c = idx % 96;
        xs[c][p] = xn[((size_t)b * NN + n0 + p) * NC + c];
    }
    __syncthreads();

    float acc[24];
    #pragma unroll
    for (int j = 0; j < 24; ++j) acc[j] = 0.f;
    const float* wrow = wsm + w * 24 * 96;
    for (int c4 = 0; c4 < 24; ++c4) {
        float x0 = xs[c4*4+0][lane], x1 = xs[c4*4+1][lane];
        float x2 = xs[c4*4+2][lane], x3 = xs[c4*4+3][lane];
        #pragma unroll
        for (int j = 0; j < 24; ++j) {
            float4 w4 = *(const float4*)(wrow + j * 96 + c4 * 4);
            acc[j] = fmaf(x0, w4.x, fmaf(x1, w4.y, fmaf(x2, w4.z, fmaf(x3, w4.w, acc[j]))));
        }
    }
    __syncthreads();   // xs dead
    #pragma unroll
    for (int j = 0; j < 24; ++j) st[lane][w * 24 + j] = acc[j];
    __syncthreads();
    float* outp = (g < 2) ? xcout : zout;
    int co = (g & 1) * 96;
    for (int idx = t; idx < 64 * 24; idx += 256) {
        int p = idx / 24, o4 = idx % 24;
        *(float4*)&outp[((size_t)b * NN + n0 + p) * DI + co + o4 * 4] = *(const float4*)&st[p][o4 * 4];
    }
}

// ------- D: conv+silu + x_proj + dt_proj, 16-pos tiles, 4-way K-split -------
__launch_bounds__(256, 4)
__global__ void k_conv_xdt(const float* __restrict__ cw, const float* __restrict__ cb,
                           const float* __restrict__ xpw, const float* __restrict__ dpw,
                           const float* __restrict__ dpb, const float* __restrict__ xcin,
                           float* __restrict__ xcvout, float* __restrict__ dtout,
                           float* __restrict__ bmout, float* __restrict__ cmout) {
    __shared__ float xcv[16][196];             // reused as dt stage at the end
    __shared__ float dtrT[DTRK][16];
    __shared__ float bc[16][33];
    int b = blockIdx.y, n0 = blockIdx.x * 16, t = threadIdx.x;
    int lane = t & 63, w = t >> 6;
    int p = lane & 15, q = lane >> 4;

    // conv + silu
    for (int idx = t; idx < 16 * DI; idx += 256) {
        int pp = idx / DI, d = idx % DI;
        float s = cb[d];
        #pragma unroll
        for (int k = 0; k < 4; ++k) {
            int n = n0 + pp - 3 + k;
            float xv = (n >= 0) ? xcin[((size_t)b * NN + n) * DI + d] : 0.f;
            s = fmaf(cw[d * 4 + k], xv, s);
        }
        s = s / (1.f + expf(-s));
        xcv[pp][d] = s;
        xcvout[((size_t)b * NN + n0 + pp) * DI + d] = s;
    }
    __syncthreads();

    // x_proj: lane=(p,q); q = K-quarter; wave w -> outputs e = w+4j
    float acc[10];
    #pragma unroll
    for (int j = 0; j < 10; ++j) acc[j] = 0.f;
    for (int ci = 0; ci < 12; ++ci) {
        int c4 = q * 12 + ci;
        float4 xv = *(const float4*)&xcv[p][c4 * 4];
        #pragma unroll
        for (int j = 0; j < 10; ++j) {
            int e = w + 4 * j;
            if (e < 38) {
                float4 w4 = *(const float4*)&xpw[(size_t)e * DI + c4 * 4];
                acc[j] = fmaf(xv.x, w4.x, fmaf(xv.y, w4.y, fmaf(xv.z, w4.z, fmaf(xv.w, w4.w, acc[j]))));
            }
        }
    }
    #pragma unroll
    for (int j = 0; j < 10; ++j) {
        acc[j] += __shfl_xor(acc[j], 16);
        acc[j] += __shfl_xor(acc[j], 32);
    }
    if (lane < 16) {
        #pragma unroll
        for (int j = 0; j < 10; ++j) {
            int e = w + 4 * j;
            if (e < DTRK) dtrT[e][p] = acc[j];
            else if (e < 38) bc[p][e - DTRK] = acc[j];
        }
    }
    __syncthreads();

    // Bm/Cm coalesced
    for (int idx = t; idx < 16 * DS; idx += 256) {
        int pp = idx / DS, si = idx % DS;
        int n = b * NN + n0 + pp;
        bmout[(size_t)n * DS + si] = bc[pp][si];
        cmout[(size_t)n * DS + si] = bc[pp][DS + si];
    }

    // dt_proj + softplus: lane=(p,q): d = q*48 + w*12 + jd
    float dv[12];
    {
        int d0 = q * 48 + w * 12;
        #pragma unroll
        for (int jd = 0; jd < 12; ++jd) {
            int d = d0 + jd;
            float v = dpb[d];
            #pragma unroll
            for (int r = 0; r < DTRK; ++r) v = fmaf(dpw[d * DTRK + r], dtrT[r][p], v);
            v = (v > 20.f) ? v : log1pf(expf(v));
            dv[jd] = v;
        }
    }
    __syncthreads();   // xcv reads all done; safe to overwrite
    {
        int d0 = q * 48 + w * 12;
        #pragma unroll
        for (int jd = 0; jd < 12; ++jd) xcv[p][d0 + jd] = dv[jd];
    }
    __syncthreads();
    for (int idx = t; idx < 16 * 48; idx += 256) {
        int pp = idx / 48, o4 = idx % 48;
        *(float4*)&dtout[((size_t)b * NN + n0 + pp) * DI + o4 * 4] = *(const float4*)&xcv[pp][o4 * 4];
    }
}

// ------- E: scan phase 1 — lane owns 8 states of one d; direct coalesced loads -------
__launch_bounds__(256)
__global__ void k_scan1(const float* __restrict__ aexp, const float* __restrict__ dt,
                        const float* __restrict__ xcv, const float* __restrict__ bm,
                        float* __restrict__ ca, float* __restrict__ cbv) {
    int t = threadIdx.x, w = t >> 6, l = t & 63;
    int T = blockIdx.x * 4 + w;                 // 1920 wave-tasks
    int b = T / (KCH * 6), rem = T % (KCH * 6);
    int kc = rem / 6, dg = rem % 6;
    int dl = l & 31, sh = l >> 5;
    int d = dg * 32 + dl;
    float a[8];
    {
        const float4* a4 = (const float4*)&aexp[d * DS + sh * 8];
        float4 a0 = a4[0], a1 = a4[1];
        a[0]=a0.x; a[1]=a0.y; a[2]=a0.z; a[3]=a0.w;
        a[4]=a1.x; a[5]=a1.y; a[6]=a1.z; a[7]=a1.w;
    }
    size_t nbase = (size_t)b * NN + kc * LCH;
    float ap[8], hb[8];
    #pragma unroll
    for (int j = 0; j < 8; ++j) { ap[j] = 1.f; hb[j] = 0.f; }
    for (int i = 0; i < LCH; ++i) {
        size_t g = (nbase + i) * DI + d;
        float dtv = dt[g];
        float xv  = xcv[g];
        const float4* b4 = (const float4*)&bm[(nbase + i) * DS + sh * 8];
        float4 b0 = b4[0], b1 = b4[1];
        float bmv[8] = {b0.x,b0.y,b0.z,b0.w,b1.x,b1.y,b1.z,b1.w};
        float bx_ = dtv * xv;
        #pragma unroll
        for (int j = 0; j < 8; ++j) {
            float dA = __expf(dtv * a[j]);
            ap[j] *= dA;
            hb[j] = fmaf(dA, hb[j], bx_ * bmv[j]);
        }
    }
    size_t cidx = ((size_t)(b * KCH + kc) * DI + d) * DS + sh * 8;
    *(float4*)&ca[cidx]      = make_float4(ap[0],ap[1],ap[2],ap[3]);
    *(float4*)&ca[cidx + 4]  = make_float4(ap[4],ap[5],ap[6],ap[7]);
    *(float4*)&cbv[cidx]     = make_float4(hb[0],hb[1],hb[2],hb[3]);
    *(float4*)&cbv[cidx + 4] = make_float4(hb[4],hb[5],hb[6],hb[7]);
}

// ------- F: scan phase 2 — sequential over chunks (hs aliases ca: no restrict) -------
__global__ void k_scan2(const float* ca, const float* cbv, float* hs) {
    int tid = blockIdx.x * 64 + threadIdx.x; // 6144 total
    int b = tid / (DI * DS), ds_ = tid % (DI * DS);
    float h = 0.f;
    for (int kc = 0; kc < KCH; ++kc) {
        size_t idx = (size_t)(b * KCH + kc) * (DI * DS) + ds_;
        float av = ca[idx];
        float bv2 = cbv[idx];
        hs[idx] = h;
        h = fmaf(av, h, bv2);
    }
}

// ------- G: scan phase 3 — replay + y + gate; 8 states/lane, 1 shfl/step -------
__launch_bounds__(256)
__global__ void k_scan3(const float* __restrict__ aexp, const float* __restrict__ Dp,
                        const float* __restrict__ dt, const float* __restrict__ xcv,
                        const float* __restrict__ bm, const float* __restrict__ cm,
                        const float* __restrict__ zin, const float* hs,
                        float* __restrict__ yout) {
    int t = threadIdx.x, w = t >> 6, l = t & 63;
    int T = blockIdx.x * 4 + w;
    int b = T / (KCH * 6), rem = T % (KCH * 6);
    int kc = rem / 6, dg = rem % 6;
    int dl = l & 31, sh = l >> 5;
    int d = dg * 32 + dl;
    float a[8];
    {
        const float4* a4 = (const float4*)&aexp[d * DS + sh * 8];
        float4 a0 = a4[0], a1 = a4[1];
        a[0]=a0.x; a[1]=a0.y; a[2]=a0.z; a[3]=a0.w;
        a[4]=a1.x; a[5]=a1.y; a[6]=a1.z; a[7]=a1.w;
    }
    float dpar = Dp[d];
    size_t nbase = (size_t)b * NN + kc * LCH;
    size_t cidx = ((size_t)(b * KCH + kc) * DI + d) * DS + sh * 8;
    float h[8];
    {
        float4 h0 = *(const float4*)&hs[cidx];
        float4 h1 = *(const float4*)&hs[cidx + 4];
        h[0]=h0.x; h[1]=h0.y; h[2]=h0.z; h[3]=h0.w;
        h[4]=h1.x; h[5]=h1.y; h[6]=h1.z; h[7]=h1.w;
    }
    for (int i = 0; i < LCH; ++i) {
        size_t g = (nbase + i) * DI + d;
        float dtv = dt[g];
        float xv  = xcv[g];
        float zv  = zin[g];
        size_t sb = (nbase + i) * DS + sh * 8;
        const float4* b4 = (const float4*)&bm[sb];
        const float4* c4p = (const float4*)&cm[sb];
        float4 b0 = b4[0], b1 = b4[1];
        float4 c0 = c4p[0], c1 = c4p[1];
        float bmv[8] = {b0.x,b0.y,b0.z,b0.w,b1.x,b1.y,b1.z,b1.w};
        float cmv[8] = {c0.x,c0.y,c0.z,c0.w,c1.x,c1.y,c1.z,c1.w};
        float bx_ = dtv * xv;
        float py = 0.f;
        #pragma unroll
        for (int j = 0; j < 8; ++j) {
            float dA = __expf(dtv * a[j]);
            h[j] = fmaf(dA, h[j], bx_ * bmv[j]);
            py = fmaf(h[j], cmv[j], py);
        }
        py += __shfl_xor(py, 32);
        if (l < 32) {
            float y = py + dpar * xv;
            y *= zv / (1.f + __expf(-zv));
            yout[g] = y;
        }
    }
}

// ------- H: out_proj (192 -> 96), W-tile in LDS, lane=position -------
__launch_bounds__(256, 2)
__global__ void k_outproj(const float* __restrict__ ow, const float* __restrict__ yin,
                          float* __restrict__ yp) {
    __shared__ float wsm[32 * 192];            // 24.6 KB: W rows [g*32, g*32+32)
    __shared__ float yt[64][193];              // 49.4 KB
    float (*yo)[40] = (float(*)[40])wsm;       // union after GEMM (10.2 KB)
    int b = blockIdx.z, g = blockIdx.y, n0 = blockIdx.x * 64, t = threadIdx.x;
    int lane = t & 63, w = t >> 6;

    const float4* wsrc = (const float4*)(ow + (size_t)g * 32 * DI);
    for (int i = t; i < 32 * 192 / 4; i += 256) ((float4*)wsm)[i] = wsrc[i];
    for (int idx = t; idx < 64 * 48; idx += 256) {
        int p = idx / 48, c4 = idx % 48;
        float4 v = *(const float4*)&yin[((size_t)b * NN + n0 + p) * DI + c4 * 4];
        yt[p][c4*4+0] = v.x; yt[p][c4*4+1] = v.y;
        yt[p][c4*4+2] = v.z; yt[p][c4*4+3] = v.w;
    }
    __syncthreads();

    float acc[8];
    #pragma unroll
    for (int j = 0; j < 8; ++j) acc[j] = 0.f;
    const float* wrow = wsm + w * 8 * 192;
    for (int c4 = 0; c4 < 48; ++c4) {
        float y0 = yt[lane][c4*4+0], y1 = yt[lane][c4*4+1];
        float y2 = yt[lane][c4*4+2], y3 = yt[lane][c4*4+3];
        #pragma unroll
        for (int j = 0; j < 8; ++j) {
            float4 w4 = *(const float4*)(wrow + j * 192 + c4 * 4);
            acc[j] = fmaf(y0, w4.x, fmaf(y1, w4.y, fmaf(y2, w4.z, fmaf(y3, w4.w, acc[j]))));
        }
    }
    __syncthreads();   // wsm dead -> yo
    #pragma unroll
    for (int j = 0; j < 8; ++j) yo[lane][w * 8 + j] = acc[j];
    __syncthreads();
    for (int idx = t; idx < 64 * 8; idx += 256) {
        int p = idx / 8, o4 = idx % 8;
        *(float4*)&yp[((size_t)b * NN + n0 + p) * NC + g * 32 + o4 * 4] = *(const float4*)&yo[p][o4 * 4];
    }
}

// ---------------- I: gather rows by rank + transpose + coalesced final write ----------------
__launch_bounds__(256)
__global__ void k_final(const float* __restrict__ yp, const int* __restrict__ rank,
                        float* __restrict__ out) {
    __shared__ float ft[64][97];
    __shared__ int rk[64];
    int b = blockIdx.y, i0 = blockIdx.x * 64, t = threadIdx.x;
    if (t < 64) rk[t] = rank[i0 + t];
    __syncthreads();
    for (int idx = t; idx < 64 * 24; idx += 256) {
        int ii = idx / 24, j = idx % 24;
        float4 v = *(const float4*)&yp[((size_t)b * NN + rk[ii]) * NC + j * 4];
        ft[ii][j * 4 + 0] = v.x; ft[ii][j * 4 + 1] = v.y;
        ft[ii][j * 4 + 2] = v.z; ft[ii][j * 4 + 3] = v.w;
    }
    __syncthreads();
    for (int idx = t; idx < 96 * 64; idx += 256) {
        int c = idx >> 6, ii = idx & 63;
        out[((size_t)b * NC + c) * NN + i0 + ii] = ft[ii][c];
    }
}

extern "C" void kernel_launch(void* const* d_in, const int* in_sizes, int n_in,
                              void* d_out, int out_size, void* d_ws, size_t ws_size,
                              hipStream_t stream) {
    const float* x    = (const float*)d_in[0];
    const float* pv   = (const float*)d_in[1];
    const float* nw   = (const float*)d_in[2];
    const float* nbp  = (const float*)d_in[3];
    const float* win  = (const float*)d_in[4];
    const float* cw   = (const float*)d_in[5];
    const float* cb   = (const float*)d_in[6];
    const float* xpw  = (const float*)d_in[7];
    const float* dpw  = (const float*)d_in[8];
    const float* dpb  = (const float*)d_in[9];
    const float* alog = (const float*)d_in[10];
    const float* Dp   = (const float*)d_in[11];
    const float* ow   = (const float*)d_in[12];
    float* out = (float*)d_out;
    float* ws  = (float*)d_ws;

    float* keys = ws + OFF_KEYS;
    int*   rank = (int*)ws + OFF_RANK;
    float* aexp = ws + OFF_AEXP;
    float* xc   = ws + OFF_XC;
    float* z    = ws + OFF_Z;
    float* xcv  = ws + OFF_XCV;
    float* dt   = ws + OFF_DT;
    float* bmb  = ws + OFF_BM;
    float* cmb  = ws + OFF_CM;
    float* ca   = ws + OFF_CA;
    float* cbv  = ws + OFF_CB;
    float* hs   = ws + OFF_CA;  // alias: in-place with ca (scan2 reads ca[idx] before writing hs[idx])
    float* xn   = ws + OFF_CA;  // alias: ca/cb not yet live (scan1 runs later)
    float* y    = ws + OFF_XC;  // alias: xc dead after conv stage
    float* yp   = ws + OFF_DT;  // alias: dt dead after scan3

    hipMemsetAsync(rank, 0, NN * sizeof(int), stream);
    k_keys<<<(NN + DI * DS + 255) / 256, 256, 0, stream>>>(pv, alog, keys, aexp);
    k_rank<<<dim3(32, 32), 256, 0, stream>>>(keys, rank);
    k_ln<<<dim3(125, 2), 256, 0, stream>>>(x, nw, nbp, rank, xn);
    k_inproj<<<dim3(125, 4, 2), 256, 0, stream>>>(xn, win, xc, z);
    k_conv_xdt<<<dim3(500, 2), 256, 0, stream>>>(cw, cb, xpw, dpw, dpb, xc, xcv, dt, bmb, cmb);
    k_scan1<<<(NB * KCH * 6) / 4, 256, 0, stream>>>(aexp, dt, xcv, bmb, ca, cbv);
    k_scan2<<<96, 64, 0, stream>>>(ca, cbv, hs);
    k_scan3<<<(NB * KCH * 6) / 4, 256, 0, stream>>>(aexp, Dp, dt, xcv, bmb, cmb, z, hs, y);
    k_outproj<<<dim3(125, 3, 2), 256, 0, stream>>>(ow, y, yp);
    k_final<<<dim3(125, 2), 256, 0, stream>>>(yp, rank, out);
}

// Round 8
// 238.634 us; speedup vs baseline: 1.0142x; 1.0142x over previous
//
#include <hip/hip_runtime.h>
#include <math.h>

#define NB 2
#define NC 96
#define NN 8000
#define DI 192
#define DS 16
#define DTRK 6
#define KCH 160
#define LCH 50

// ws layout (element offsets, 4B each)
#define OFF_KEYS 0
#define OFF_RANK 8000
#define OFF_AEXP 24000
#define OFF_XC   32768                        // (B,N,DI) — reused as Y after scan
#define OFF_Z    (OFF_XC  + NB*NN*DI)
#define OFF_XCV  (OFF_Z   + NB*NN*DI)
#define OFF_DT   (OFF_XCV + NB*NN*DI)         // reused as YP (B,N,96) after scan3
#define OFF_BM   (OFF_DT  + NB*NN*DI)
#define OFF_CM   (OFF_BM  + NB*NN*DS)
#define OFF_CA   (OFF_CM  + NB*NN*DS)         // xn (B,N,96) aliases ca+cb (pre-scan); hs aliases ca
#define OFF_CB   (OFF_CA  + NB*KCH*DI*DS)

// ---------------- A1: projection keys + A = -exp(A_log) + rank zero-init ----------------
__global__ void k_keys(const float* __restrict__ pv, const float* __restrict__ alog,
                       float* __restrict__ keys, float* __restrict__ aexp,
                       int* __restrict__ rank) {
    int t = blockIdx.x * 256 + threadIdx.x;
    if (t < NN) {
        int z = t / 400, rem = t % 400, y = rem / 20, x = rem % 20;
        keys[t] = (float)z * pv[0] + (float)y * pv[1] + (float)x * pv[2];
        rank[t] = 0;
    } else if (t < NN + DI * DS) {
        int i = t - NN;
        aexp[i] = -expf(alog[i]);
    }
}

// ---------------- A2: O(N^2) stable rank (tie-break on index), 1000-key chunks ----------------
__global__ void k_rank(const float* __restrict__ keys, int* __restrict__ rank) {
    __shared__ float kj[1000];
    int t = threadIdx.x;
    int j0 = blockIdx.y * 1000;
    for (int j = t; j < 1000; j += 256) kj[j] = keys[j0 + j];
    __syncthreads();
    int i = blockIdx.x * 256 + t;
    if (i >= NN) return;
    float ki = keys[i];
    int cnt = 0;
    #pragma unroll 4
    for (int j = 0; j < 1000; ++j) {
        float kv = kj[j];
        int jj = j0 + j;
        cnt += (kv < ki || (kv == ki && jj < i)) ? 1 : 0;
    }
    atomicAdd(rank + i, cnt);
}

// ------- B1: LayerNorm + row-scatter to sorted xn (B,N,96) -------
__launch_bounds__(256)
__global__ void k_ln(const float* __restrict__ x, const float* __restrict__ nw,
                     const float* __restrict__ nbp, const int* __restrict__ rank,
                     float* __restrict__ xn) {
    __shared__ float xt[64][100];
    __shared__ int rk[64];
    __shared__ float nwb[NC], nbb[NC];
    int b = blockIdx.y, n0 = blockIdx.x * 64, t = threadIdx.x;
    int lane = t & 63, w = t >> 6;
    if (t < 64) rk[t] = rank[n0 + t];
    else if (t < 160) { int c = t - 64; nwb[c] = nw[c]; nbb[c] = nbp[c]; }
    for (int idx = t; idx < NC * 64; idx += 256) {
        int c = idx >> 6, p = idx & 63;
        xt[p][c] = x[((size_t)b * NC + c) * NN + n0 + p];
    }
    __syncthreads();
    // per-lane LN (4 waves redundant)
    float xr[96];
    float s = 0.f, sq = 0.f;
    #pragma unroll
    for (int c4 = 0; c4 < 24; ++c4) {
        float4 v = *(const float4*)&xt[lane][c4 * 4];
        xr[c4*4+0] = v.x; xr[c4*4+1] = v.y; xr[c4*4+2] = v.z; xr[c4*4+3] = v.w;
        s += v.x + v.y + v.z + v.w;
        sq += v.x*v.x + v.y*v.y + v.z*v.z + v.w*v.w;
    }
    float mu = s * (1.f / 96.f);
    float var = sq * (1.f / 96.f) - mu * mu;
    float rs = rsqrtf(var + 1e-5f);
    #pragma unroll
    for (int c = 0; c < 96; ++c) xr[c] = (xr[c] - mu) * rs * nwb[c] + nbb[c];
    __syncthreads();
    if (w == 0) {
        #pragma unroll
        for (int c = 0; c < 96; ++c) xt[lane][c] = xr[c];
    }
    __syncthreads();
    for (int idx = t; idx < 64 * 24; idx += 256) {
        int p = idx / 24, c4 = idx % 24;
        *(float4*)&xn[((size_t)b * NN + rk[p]) * NC + c4 * 4] = *(const float4*)&xt[p][c4 * 4];
    }
}

// ------- B2: in_proj GEMM, W-tile staged in LDS, uniform broadcast reads -------
__launch_bounds__(256, 2)
__global__ void k_inproj(const float* __restrict__ xn, const float* __restrict__ win,
                         float* __restrict__ xcout, float* __restrict__ zout) {
    __shared__ float wsm[96 * 96];             // 36.9 KB: W rows [g*96, g*96+96)
    __shared__ float smem[64 * 104];           // union: xs[96][65] then st[64][104]
    float (*xs)[65]  = (float(*)[65])smem;
    float (*st)[104] = (float(*)[104])smem;
    int b = blockIdx.z, g = blockIdx.y, n0 = blockIdx.x * 64, t = threadIdx.x;
    int lane = t & 63, w = t >> 6;

    const float4* wsrc = (const float4*)(win + (size_t)g * 96 * NC);
    for (int i = t; i < 96 * 96 / 4; i += 256) ((float4*)wsm)[i] = wsrc[i];
    for (int idx = t; idx < 64 * 96; idx += 256) {
        int p = idx / 96, c = idx % 96;
        xs[c][p] = xn[((size_t)b * NN + n0 + p) * NC + c];
    }
    __syncthreads();

    float acc[24];
    #pragma unroll
    for (int j = 0; j < 24; ++j) acc[j] = 0.f;
    const float* wrow = wsm + w * 24 * 96;
    for (int c4 = 0; c4 < 24; ++c4) {
        float x0 = xs[c4*4+0][lane], x1 = xs[c4*4+1][lane];
        float x2 = xs[c4*4+2][lane], x3 = xs[c4*4+3][lane];
        #pragma unroll
        for (int j = 0; j < 24; ++j) {
            float4 w4 = *(const float4*)(wrow + j * 96 + c4 * 4);
            acc[j] = fmaf(x0, w4.x, fmaf(x1, w4.y, fmaf(x2, w4.z, fmaf(x3, w4.w, acc[j]))));
        }
    }
    __syncthreads();   // xs dead
    #pragma unroll
    for (int j = 0; j < 24; ++j) st[lane][w * 24 + j] = acc[j];
    __syncthreads();
    float* outp = (g < 2) ? xcout : zout;
    int co = (g & 1) * 96;
    for (int idx = t; idx < 64 * 24; idx += 256) {
        int p = idx / 24, o4 = idx % 24;
        *(float4*)&outp[((size_t)b * NN + n0 + p) * DI + co + o4 * 4] = *(const float4*)&st[p][o4 * 4];
    }
}

// ------- D: conv+silu + x_proj + dt_proj, 8-pos tiles, staged weights, fast math -------
__launch_bounds__(256, 8)
__global__ void k_conv_xdt(const float* __restrict__ cw, const float* __restrict__ cb,
                           const float* __restrict__ xpw, const float* __restrict__ dpw,
                           const float* __restrict__ dpb, const float* __restrict__ xcin,
                           float* __restrict__ xcvout, float* __restrict__ dtout,
                           float* __restrict__ bmout, float* __restrict__ cmout) {
    __shared__ float xcv[8][196];              // reused as dt stage at the end
    __shared__ float dtrT[DTRK][9];            // [r][p]
    __shared__ float bc[8][33];
    __shared__ float cwT[4][DI];
    __shared__ float dpwT[DTRK][DI];
    __shared__ float cbl[DI], dpbl[DI];
    int b = blockIdx.y, n0 = blockIdx.x * 8, t = threadIdx.x;
    int l = t & 63, w = t >> 6;
    int p = l & 7, q = l >> 3;

    if (t < DI) {
        cbl[t] = cb[t];
        dpbl[t] = dpb[t];
        #pragma unroll
        for (int k = 0; k < 4; ++k) cwT[k][t] = cw[t * 4 + k];
        #pragma unroll
        for (int r = 0; r < DTRK; ++r) dpwT[r][t] = dpw[t * DTRK + r];
    }
    __syncthreads();

    // conv + silu: 8*192 elems, 6 iters, incremental (pp,d)
    {
        int pp = t / DI, d = t - pp * DI;
        #pragma unroll
        for (int i = 0; i < 6; ++i) {
            float s = cbl[d];
            #pragma unroll
            for (int k = 0; k < 4; ++k) {
                int n = n0 + pp - 3 + k;
                float xv = (n >= 0) ? xcin[((size_t)b * NN + n) * DI + d] : 0.f;
                s = fmaf(cwT[k][d], xv, s);
            }
            s = s * __builtin_amdgcn_rcpf(1.f + __expf(-s));
            xcv[pp][d] = s;
            xcvout[((size_t)b * NN + n0 + pp) * DI + d] = s;
            pp += 1; d += 64;
            if (d >= DI) { d -= DI; pp += 1; }
        }
    }
    __syncthreads();

    // x_proj: lane=(p,q); q = K-eighth (24 chans); wave w -> outputs e = w+4j
    float acc[10];
    #pragma unroll
    for (int j = 0; j < 10; ++j) acc[j] = 0.f;
    #pragma unroll
    for (int ci = 0; ci < 6; ++ci) {
        int c4 = q * 6 + ci;
        float4 xv = *(const float4*)&xcv[p][c4 * 4];
        #pragma unroll
        for (int j = 0; j < 10; ++j) {
            int e = w + 4 * j;
            if (e < 38) {
                float4 w4 = *(const float4*)&xpw[(size_t)e * DI + c4 * 4];
                acc[j] = fmaf(xv.x, w4.x, fmaf(xv.y, w4.y, fmaf(xv.z, w4.z, fmaf(xv.w, w4.w, acc[j]))));
            }
        }
    }
    #pragma unroll
    for (int j = 0; j < 10; ++j) {
        acc[j] += __shfl_xor(acc[j], 8);
        acc[j] += __shfl_xor(acc[j], 16);
        acc[j] += __shfl_xor(acc[j], 32);
    }
    if (l < 8) {
        #pragma unroll
        for (int j = 0; j < 10; ++j) {
            int e = w + 4 * j;
            if (e < DTRK) dtrT[e][p] = acc[j];
            else if (e < 38) bc[p][e - DTRK] = acc[j];
        }
    }
    __syncthreads();

    // Bm/Cm coalesced
    if (t < 8 * DS) {
        int pp = t >> 4, si = t & 15;
        int n = b * NN + n0 + pp;
        bmout[(size_t)n * DS + si] = bc[pp][si];
        cmout[(size_t)n * DS + si] = bc[pp][DS + si];
    }

    // dt_proj + softplus: lane=(p,q): d = q*24 + w*6 + jd
    float dv[6];
    {
        int d0 = q * 24 + w * 6;
        #pragma unroll
        for (int jd = 0; jd < 6; ++jd) {
            int d = d0 + jd;
            float v = dpbl[d];
            #pragma unroll
            for (int r = 0; r < DTRK; ++r) v = fmaf(dpwT[r][d], dtrT[r][p], v);
            v = (v > 20.f) ? v : __logf(1.f + __expf(v));
            dv[jd] = v;
        }
    }
    __syncthreads();   // xcv reads all done; safe to overwrite
    {
        int d0 = q * 24 + w * 6;
        #pragma unroll
        for (int jd = 0; jd < 6; ++jd) xcv[p][d0 + jd] = dv[jd];
    }
    __syncthreads();
    for (int idx = t; idx < 8 * 48; idx += 256) {
        int pp = idx / 48, o4 = idx % 48;
        *(float4*)&dtout[((size_t)b * NN + n0 + pp) * DI + o4 * 4] = *(const float4*)&xcv[pp][o4 * 4];
    }
}

// ------- E: scan phase 1 — lane owns 8 states of one d; direct coalesced loads -------
__launch_bounds__(256)
__global__ void k_scan1(const float* __restrict__ aexp, const float* __restrict__ dt,
                        const float* __restrict__ xcv, const float* __restrict__ bm,
                        float* __restrict__ ca, float* __restrict__ cbv) {
    int t = threadIdx.x, w = t >> 6, l = t & 63;
    int T = blockIdx.x * 4 + w;                 // 1920 wave-tasks
    int b = T / (KCH * 6), rem = T % (KCH * 6);
    int kc = rem / 6, dg = rem % 6;
    int dl = l & 31, sh = l >> 5;
    int d = dg * 32 + dl;
    float a[8];
    {
        const float4* a4 = (const float4*)&aexp[d * DS + sh * 8];
        float4 a0 = a4[0], a1 = a4[1];
        a[0]=a0.x; a[1]=a0.y; a[2]=a0.z; a[3]=a0.w;
        a[4]=a1.x; a[5]=a1.y; a[6]=a1.z; a[7]=a1.w;
    }
    size_t nbase = (size_t)b * NN + kc * LCH;
    float ap[8], hb[8];
    #pragma unroll
    for (int j = 0; j < 8; ++j) { ap[j] = 1.f; hb[j] = 0.f; }
    for (int i = 0; i < LCH; ++i) {
        size_t g = (nbase + i) * DI + d;
        float dtv = dt[g];
        float xv  = xcv[g];
        const float4* b4 = (const float4*)&bm[(nbase + i) * DS + sh * 8];
        float4 b0 = b4[0], b1 = b4[1];
        float bmv[8] = {b0.x,b0.y,b0.z,b0.w,b1.x,b1.y,b1.z,b1.w};
        float bx_ = dtv * xv;
        #pragma unroll
        for (int j = 0; j < 8; ++j) {
            float dA = __expf(dtv * a[j]);
            ap[j] *= dA;
            hb[j] = fmaf(dA, hb[j], bx_ * bmv[j]);
        }
    }
    size_t cidx = ((size_t)(b * KCH + kc) * DI + d) * DS + sh * 8;
    *(float4*)&ca[cidx]      = make_float4(ap[0],ap[1],ap[2],ap[3]);
    *(float4*)&ca[cidx + 4]  = make_float4(ap[4],ap[5],ap[6],ap[7]);
    *(float4*)&cbv[cidx]     = make_float4(hb[0],hb[1],hb[2],hb[3]);
    *(float4*)&cbv[cidx + 4] = make_float4(hb[4],hb[5],hb[6],hb[7]);
}

// ------- F: scan phase 2 — sequential over chunks (hs aliases ca: no restrict) -------
__global__ void k_scan2(const float* ca, const float* cbv, float* hs) {
    int tid = blockIdx.x * 64 + threadIdx.x; // 6144 total
    int b = tid / (DI * DS), ds_ = tid % (DI * DS);
    float h = 0.f;
    for (int kc = 0; kc < KCH; ++kc) {
        size_t idx = (size_t)(b * KCH + kc) * (DI * DS) + ds_;
        float av = ca[idx];
        float bv2 = cbv[idx];
        hs[idx] = h;
        h = fmaf(av, h, bv2);
    }
}

// ------- G: scan phase 3 — replay + y + gate; 8 states/lane, 1 shfl/step -------
__launch_bounds__(256)
__global__ void k_scan3(const float* __restrict__ aexp, const float* __restrict__ Dp,
                        const float* __restrict__ dt, const float* __restrict__ xcv,
                        const float* __restrict__ bm, const float* __restrict__ cm,
                        const float* __restrict__ zin, const float* hs,
                        float* __restrict__ yout) {
    int t = threadIdx.x, w = t >> 6, l = t & 63;
    int T = blockIdx.x * 4 + w;
    int b = T / (KCH * 6), rem = T % (KCH * 6);
    int kc = rem / 6, dg = rem % 6;
    int dl = l & 31, sh = l >> 5;
    int d = dg * 32 + dl;
    float a[8];
    {
        const float4* a4 = (const float4*)&aexp[d * DS + sh * 8];
        float4 a0 = a4[0], a1 = a4[1];
        a[0]=a0.x; a[1]=a0.y; a[2]=a0.z; a[3]=a0.w;
        a[4]=a1.x; a[5]=a1.y; a[6]=a1.z; a[7]=a1.w;
    }
    float dpar = Dp[d];
    size_t nbase = (size_t)b * NN + kc * LCH;
    size_t cidx = ((size_t)(b * KCH + kc) * DI + d) * DS + sh * 8;
    float h[8];
    {
        float4 h0 = *(const float4*)&hs[cidx];
        float4 h1 = *(const float4*)&hs[cidx + 4];
        h[0]=h0.x; h[1]=h0.y; h[2]=h0.z; h[3]=h0.w;
        h[4]=h1.x; h[5]=h1.y; h[6]=h1.z; h[7]=h1.w;
    }
    for (int i = 0; i < LCH; ++i) {
        size_t g = (nbase + i) * DI + d;
        float dtv = dt[g];
        float xv  = xcv[g];
        float zv  = zin[g];
        size_t sb = (nbase + i) * DS + sh * 8;
        const float4* b4 = (const float4*)&bm[sb];
        const float4* c4p = (const float4*)&cm[sb];
        float4 b0 = b4[0], b1 = b4[1];
        float4 c0 = c4p[0], c1 = c4p[1];
        float bmv[8] = {b0.x,b0.y,b0.z,b0.w,b1.x,b1.y,b1.z,b1.w};
        float cmv[8] = {c0.x,c0.y,c0.z,c0.w,c1.x,c1.y,c1.z,c1.w};
        float bx_ = dtv * xv;
        float py = 0.f;
        #pragma unroll
        for (int j = 0; j < 8; ++j) {
            float dA = __expf(dtv * a[j]);
            h[j] = fmaf(dA, h[j], bx_ * bmv[j]);
            py = fmaf(h[j], cmv[j], py);
        }
        py += __shfl_xor(py, 32);
        if (l < 32) {
            float y = py + dpar * xv;
            y *= zv / (1.f + __expf(-zv));
            yout[g] = y;
        }
    }
}

// ------- H: out_proj (192 -> 96), W-tile in LDS, lane=position -------
__launch_bounds__(256, 2)
__global__ void k_outproj(const float* __restrict__ ow, const float* __restrict__ yin,
                          float* __restrict__ yp) {
    __shared__ float wsm[32 * 192];            // 24.6 KB: W rows [g*32, g*32+32)
    __shared__ float yt[64][193];              // 49.4 KB
    float (*yo)[40] = (float(*)[40])wsm;       // union after GEMM (10.2 KB)
    int b = blockIdx.z, g = blockIdx.y, n0 = blockIdx.x * 64, t = threadIdx.x;
    int lane = t & 63, w = t >> 6;

    const float4* wsrc = (const float4*)(ow + (size_t)g * 32 * DI);
    for (int i = t; i < 32 * 192 / 4; i += 256) ((float4*)wsm)[i] = wsrc[i];
    for (int idx = t; idx < 64 * 48; idx += 256) {
        int p = idx / 48, c4 = idx % 48;
        float4 v = *(const float4*)&yin[((size_t)b * NN + n0 + p) * DI + c4 * 4];
        yt[p][c4*4+0] = v.x; yt[p][c4*4+1] = v.y;
        yt[p][c4*4+2] = v.z; yt[p][c4*4+3] = v.w;
    }
    __syncthreads();

    float acc[8];
    #pragma unroll
    for (int j = 0; j < 8; ++j) acc[j] = 0.f;
    const float* wrow = wsm + w * 8 * 192;
    for (int c4 = 0; c4 < 48; ++c4) {
        float y0 = yt[lane][c4*4+0], y1 = yt[lane][c4*4+1];
        float y2 = yt[lane][c4*4+2], y3 = yt[lane][c4*4+3];
        #pragma unroll
        for (int j = 0; j < 8; ++j) {
            float4 w4 = *(const float4*)(wrow + j * 192 + c4 * 4);
            acc[j] = fmaf(y0, w4.x, fmaf(y1, w4.y, fmaf(y2, w4.z, fmaf(y3, w4.w, acc[j]))));
        }
    }
    __syncthreads();   // wsm dead -> yo
    #pragma unroll
    for (int j = 0; j < 8; ++j) yo[lane][w * 8 + j] = acc[j];
    __syncthreads();
    for (int idx = t; idx < 64 * 8; idx += 256) {
        int p = idx / 8, o4 = idx % 8;
        *(float4*)&yp[((size_t)b * NN + n0 + p) * NC + g * 32 + o4 * 4] = *(const float4*)&yo[p][o4 * 4];
    }
}

// ---------------- I: gather rows by rank + transpose + coalesced final write ----------------
__launch_bounds__(256)
__global__ void k_final(const float* __restrict__ yp, const int* __restrict__ rank,
                        float* __restrict__ out) {
    __shared__ float ft[64][97];
    __shared__ int rk[64];
    int b = blockIdx.y, i0 = blockIdx.x * 64, t = threadIdx.x;
    if (t < 64) rk[t] = rank[i0 + t];
    __syncthreads();
    for (int idx = t; idx < 64 * 24; idx += 256) {
        int ii = idx / 24, j = idx % 24;
        float4 v = *(const float4*)&yp[((size_t)b * NN + rk[ii]) * NC + j * 4];
        ft[ii][j * 4 + 0] = v.x; ft[ii][j * 4 + 1] = v.y;
        ft[ii][j * 4 + 2] = v.z; ft[ii][j * 4 + 3] = v.w;
    }
    __syncthreads();
    for (int idx = t; idx < 96 * 64; idx += 256) {
        int c = idx >> 6, ii = idx & 63;
        out[((size_t)b * NC + c) * NN + i0 + ii] = ft[ii][c];
    }
}

extern "C" void kernel_launch(void* const* d_in, const int* in_sizes, int n_in,
                              void* d_out, int out_size, void* d_ws, size_t ws_size,
                              hipStream_t stream) {
    const float* x    = (const float*)d_in[0];
    const float* pv   = (const float*)d_in[1];
    const float* nw   = (const float*)d_in[2];
    const float* nbp  = (const float*)d_in[3];
    const float* win  = (const float*)d_in[4];
    const float* cw   = (const float*)d_in[5];
    const float* cb   = (const float*)d_in[6];
    const float* xpw  = (const float*)d_in[7];
    const float* dpw  = (const float*)d_in[8];
    const float* dpb  = (const float*)d_in[9];
    const float* alog = (const float*)d_in[10];
    const float* Dp   = (const float*)d_in[11];
    const float* ow   = (const float*)d_in[12];
    float* out = (float*)d_out;
    float* ws  = (float*)d_ws;

    float* keys = ws + OFF_KEYS;
    int*   rank = (int*)ws + OFF_RANK;
    float* aexp = ws + OFF_AEXP;
    float* xc   = ws + OFF_XC;
    float* z    = ws + OFF_Z;
    float* xcv  = ws + OFF_XCV;
    float* dt   = ws + OFF_DT;
    float* bmb  = ws + OFF_BM;
    float* cmb  = ws + OFF_CM;
    float* ca   = ws + OFF_CA;
    float* cbv  = ws + OFF_CB;
    float* hs   = ws + OFF_CA;  // alias: in-place with ca (scan2 reads ca[idx] before writing hs[idx])
    float* xn   = ws + OFF_CA;  // alias: ca/cb not yet live (scan1 runs later)
    float* y    = ws + OFF_XC;  // alias: xc dead after conv stage
    float* yp   = ws + OFF_DT;  // alias: dt dead after scan3

    k_keys<<<(NN + DI * DS + 255) / 256, 256, 0, stream>>>(pv, alog, keys, aexp, rank);
    k_rank<<<dim3(32, 8), 256, 0, stream>>>(keys, rank);
    k_ln<<<dim3(125, 2), 256, 0, stream>>>(x, nw, nbp, rank, xn);
    k_inproj<<<dim3(125, 4, 2), 256, 0, stream>>>(xn, win, xc, z);
    k_conv_xdt<<<dim3(1000, 2), 256, 0, stream>>>(cw, cb, xpw, dpw, dpb, xc, xcv, dt, bmb, cmb);
    k_scan1<<<(NB * KCH * 6) / 4, 256, 0, stream>>>(aexp, dt, xcv, bmb, ca, cbv);
    k_scan2<<<96, 64, 0, stream>>>(ca, cbv, hs);
    k_scan3<<<(NB * KCH * 6) / 4, 256, 0, stream>>>(aexp, Dp, dt, xcv, bmb, cmb, z, hs, y);
    k_outproj<<<dim3(125, 3, 2), 256, 0, stream>>>(ow, y, yp);
    k_final<<<dim3(125, 2), 256, 0, stream>>>(yp, rank, out);
}

// Round 9
// 225.111 us; speedup vs baseline: 1.0751x; 1.0601x over previous
//
#include <hip/hip_runtime.h>
#include <math.h>

#define NB 2
#define NC 96
#define NN 8000
#define DI 192
#define DS 16
#define DTRK 6
#define KCH 160
#define LCH 50

// ws layout (element offsets, 4B each)
#define OFF_KEYS 0
#define OFF_RANK 8000
#define OFF_AEXP 24000
#define OFF_XC   32768                        // (B,N,DI) — reused as Y after scan
#define OFF_Z    (OFF_XC  + NB*NN*DI)
#define OFF_XCV  (OFF_Z   + NB*NN*DI)
#define OFF_DT   (OFF_XCV + NB*NN*DI)         // reused as YP (B,N,96) after scan3
#define OFF_BM   (OFF_DT  + NB*NN*DI)
#define OFF_CM   (OFF_BM  + NB*NN*DS)
#define OFF_CA   (OFF_CM  + NB*NN*DS)         // xn (B,N,96) aliases ca+cb (pre-scan); hs aliases ca
#define OFF_CB   (OFF_CA  + NB*KCH*DI*DS)

// ---------------- A1: projection keys + A = -exp(A_log) + rank zero-init ----------------
__global__ void k_keys(const float* __restrict__ pv, const float* __restrict__ alog,
                       float* __restrict__ keys, float* __restrict__ aexp,
                       int* __restrict__ rank) {
    int t = blockIdx.x * 256 + threadIdx.x;
    if (t < NN) {
        int z = t / 400, rem = t % 400, y = rem / 20, x = rem % 20;
        keys[t] = (float)z * pv[0] + (float)y * pv[1] + (float)x * pv[2];
        rank[t] = 0;
    } else if (t < NN + DI * DS) {
        int i = t - NN;
        aexp[i] = -expf(alog[i]);
    }
}

// ---------------- A2: O(N^2) stable rank (tie-break on index), 1000-key chunks ----------------
__global__ void k_rank(const float* __restrict__ keys, int* __restrict__ rank) {
    __shared__ float kj[1000];
    int t = threadIdx.x;
    int j0 = blockIdx.y * 1000;
    for (int j = t; j < 1000; j += 256) kj[j] = keys[j0 + j];
    __syncthreads();
    int i = blockIdx.x * 256 + t;
    if (i >= NN) return;
    float ki = keys[i];
    int cnt = 0;
    #pragma unroll 4
    for (int j = 0; j < 1000; ++j) {
        float kv = kj[j];
        int jj = j0 + j;
        cnt += (kv < ki || (kv == ki && jj < i)) ? 1 : 0;
    }
    atomicAdd(rank + i, cnt);
}

// ------- B1: LayerNorm + row-scatter to sorted xn (B,N,96) -------
__launch_bounds__(256)
__global__ void k_ln(const float* __restrict__ x, const float* __restrict__ nw,
                     const float* __restrict__ nbp, const int* __restrict__ rank,
                     float* __restrict__ xn) {
    __shared__ float xt[64][100];
    __shared__ int rk[64];
    __shared__ float nwb[NC], nbb[NC];
    int b = blockIdx.y, n0 = blockIdx.x * 64, t = threadIdx.x;
    int lane = t & 63, w = t >> 6;
    if (t < 64) rk[t] = rank[n0 + t];
    else if (t < 160) { int c = t - 64; nwb[c] = nw[c]; nbb[c] = nbp[c]; }
    for (int idx = t; idx < NC * 64; idx += 256) {
        int c = idx >> 6, p = idx & 63;
        xt[p][c] = x[((size_t)b * NC + c) * NN + n0 + p];
    }
    __syncthreads();
    // per-lane LN (4 waves redundant)
    float xr[96];
    float s = 0.f, sq = 0.f;
    #pragma unroll
    for (int c4 = 0; c4 < 24; ++c4) {
        float4 v = *(const float4*)&xt[lane][c4 * 4];
        xr[c4*4+0] = v.x; xr[c4*4+1] = v.y; xr[c4*4+2] = v.z; xr[c4*4+3] = v.w;
        s += v.x + v.y + v.z + v.w;
        sq += v.x*v.x + v.y*v.y + v.z*v.z + v.w*v.w;
    }
    float mu = s * (1.f / 96.f);
    float var = sq * (1.f / 96.f) - mu * mu;
    float rs = rsqrtf(var + 1e-5f);
    #pragma unroll
    for (int c = 0; c < 96; ++c) xr[c] = (xr[c] - mu) * rs * nwb[c] + nbb[c];
    __syncthreads();
    if (w == 0) {
        #pragma unroll
        for (int c = 0; c < 96; ++c) xt[lane][c] = xr[c];
    }
    __syncthreads();
    for (int idx = t; idx < 64 * 24; idx += 256) {
        int p = idx / 24, c4 = idx % 24;
        *(float4*)&xn[((size_t)b * NN + rk[p]) * NC + c4 * 4] = *(const float4*)&xt[p][c4 * 4];
    }
}

// ------- B2: in_proj GEMM, row-major LDS tiles, 4pos x 3out threads -------
__launch_bounds__(256, 3)
__global__ void k_inproj(const float* __restrict__ xn, const float* __restrict__ win,
                         float* __restrict__ xcout, float* __restrict__ zout) {
    __shared__ float wsm[48][100];             // 19.2 KB: W rows [g*48, g*48+48)
    __shared__ float xs[64][100];              // 25.6 KB: x tile; reused as output stage
    int b = blockIdx.z, g = blockIdx.y, n0 = blockIdx.x * 64, t = threadIdx.x;

    for (int i = t; i < 48 * 24; i += 256) {
        int r = i / 24, c4 = i % 24;
        *(float4*)&wsm[r][c4 * 4] = *(const float4*)(win + (size_t)(g * 48 + r) * NC + c4 * 4);
    }
    for (int i = t; i < 64 * 24; i += 256) {
        int p = i / 24, c4 = i % 24;
        *(float4*)&xs[p][c4 * 4] = *(const float4*)(xn + ((size_t)b * NN + n0 + p) * NC + c4 * 4);
    }
    __syncthreads();

    int oi = t & 15, pi = t >> 4;              // 16 out-thr (3 outs) x 16 pos-grp (4 pos)
    float acc[3][4];
    #pragma unroll
    for (int j = 0; j < 3; ++j)
        #pragma unroll
        for (int pp = 0; pp < 4; ++pp) acc[j][pp] = 0.f;

    for (int c4 = 0; c4 < 24; ++c4) {
        float4 b0 = *(const float4*)&wsm[oi * 3 + 0][c4 * 4];
        float4 b1 = *(const float4*)&wsm[oi * 3 + 1][c4 * 4];
        float4 b2 = *(const float4*)&wsm[oi * 3 + 2][c4 * 4];
        #pragma unroll
        for (int pp = 0; pp < 4; ++pp) {
            float4 a = *(const float4*)&xs[pi * 4 + pp][c4 * 4];
            acc[0][pp] = fmaf(a.x, b0.x, fmaf(a.y, b0.y, fmaf(a.z, b0.z, fmaf(a.w, b0.w, acc[0][pp]))));
            acc[1][pp] = fmaf(a.x, b1.x, fmaf(a.y, b1.y, fmaf(a.z, b1.z, fmaf(a.w, b1.w, acc[1][pp]))));
            acc[2][pp] = fmaf(a.x, b2.x, fmaf(a.y, b2.y, fmaf(a.z, b2.z, fmaf(a.w, b2.w, acc[2][pp]))));
        }
    }
    __syncthreads();   // xs tile dead -> reuse as output stage st[64][100] cols 0..47
    #pragma unroll
    for (int j = 0; j < 3; ++j)
        #pragma unroll
        for (int pp = 0; pp < 4; ++pp) xs[pi * 4 + pp][oi * 3 + j] = acc[j][pp];
    __syncthreads();

    float* outp = (g < 4) ? xcout : zout;
    int co = (g & 3) * 48;
    for (int i = t; i < 64 * 12; i += 256) {
        int p = i / 12, o4 = i % 12;
        *(float4*)&outp[((size_t)b * NN + n0 + p) * DI + co + o4 * 4] = *(const float4*)&xs[p][o4 * 4];
    }
}

// ------- D: conv+silu + x_proj + dt_proj, 8-pos tiles, staged weights, fast math -------
__launch_bounds__(256, 8)
__global__ void k_conv_xdt(const float* __restrict__ cw, const float* __restrict__ cb,
                           const float* __restrict__ xpw, const float* __restrict__ dpw,
                           const float* __restrict__ dpb, const float* __restrict__ xcin,
                           float* __restrict__ xcvout, float* __restrict__ dtout,
                           float* __restrict__ bmout, float* __restrict__ cmout) {
    __shared__ float xcv[8][196];              // reused as dt stage at the end
    __shared__ float dtrT[DTRK][9];            // [r][p]
    __shared__ float bc[8][33];
    __shared__ float cwT[4][DI];
    __shared__ float dpwT[DTRK][DI];
    __shared__ float cbl[DI], dpbl[DI];
    int b = blockIdx.y, n0 = blockIdx.x * 8, t = threadIdx.x;
    int l = t & 63, w = t >> 6;
    int p = l & 7, q = l >> 3;

    if (t < DI) {
        cbl[t] = cb[t];
        dpbl[t] = dpb[t];
        #pragma unroll
        for (int k = 0; k < 4; ++k) cwT[k][t] = cw[t * 4 + k];
        #pragma unroll
        for (int r = 0; r < DTRK; ++r) dpwT[r][t] = dpw[t * DTRK + r];
    }
    __syncthreads();

    // conv + silu: 8*192 elems, 6 iters, incremental (pp,d)
    {
        int pp = t / DI, d = t - pp * DI;
        #pragma unroll
        for (int i = 0; i < 6; ++i) {
            float s = cbl[d];
            #pragma unroll
            for (int k = 0; k < 4; ++k) {
                int n = n0 + pp - 3 + k;
                float xv = (n >= 0) ? xcin[((size_t)b * NN + n) * DI + d] : 0.f;
                s = fmaf(cwT[k][d], xv, s);
            }
            s = s * __builtin_amdgcn_rcpf(1.f + __expf(-s));
            xcv[pp][d] = s;
            xcvout[((size_t)b * NN + n0 + pp) * DI + d] = s;
            pp += 1; d += 64;
            if (d >= DI) { d -= DI; pp += 1; }
        }
    }
    __syncthreads();

    // x_proj: lane=(p,q); q = K-eighth (24 chans); wave w -> outputs e = w+4j
    float acc[10];
    #pragma unroll
    for (int j = 0; j < 10; ++j) acc[j] = 0.f;
    #pragma unroll
    for (int ci = 0; ci < 6; ++ci) {
        int c4 = q * 6 + ci;
        float4 xv = *(const float4*)&xcv[p][c4 * 4];
        #pragma unroll
        for (int j = 0; j < 10; ++j) {
            int e = w + 4 * j;
            if (e < 38) {
                float4 w4 = *(const float4*)&xpw[(size_t)e * DI + c4 * 4];
                acc[j] = fmaf(xv.x, w4.x, fmaf(xv.y, w4.y, fmaf(xv.z, w4.z, fmaf(xv.w, w4.w, acc[j]))));
            }
        }
    }
    #pragma unroll
    for (int j = 0; j < 10; ++j) {
        acc[j] += __shfl_xor(acc[j], 8);
        acc[j] += __shfl_xor(acc[j], 16);
        acc[j] += __shfl_xor(acc[j], 32);
    }
    if (l < 8) {
        #pragma unroll
        for (int j = 0; j < 10; ++j) {
            int e = w + 4 * j;
            if (e < DTRK) dtrT[e][p] = acc[j];
            else if (e < 38) bc[p][e - DTRK] = acc[j];
        }
    }
    __syncthreads();

    // Bm/Cm coalesced
    if (t < 8 * DS) {
        int pp = t >> 4, si = t & 15;
        int n = b * NN + n0 + pp;
        bmout[(size_t)n * DS + si] = bc[pp][si];
        cmout[(size_t)n * DS + si] = bc[pp][DS + si];
    }

    // dt_proj + softplus: lane=(p,q): d = q*24 + w*6 + jd
    float dv[6];
    {
        int d0 = q * 24 + w * 6;
        #pragma unroll
        for (int jd = 0; jd < 6; ++jd) {
            int d = d0 + jd;
            float v = dpbl[d];
            #pragma unroll
            for (int r = 0; r < DTRK; ++r) v = fmaf(dpwT[r][d], dtrT[r][p], v);
            v = (v > 20.f) ? v : __logf(1.f + __expf(v));
            dv[jd] = v;
        }
    }
    __syncthreads();   // xcv reads all done; safe to overwrite
    {
        int d0 = q * 24 + w * 6;
        #pragma unroll
        for (int jd = 0; jd < 6; ++jd) xcv[p][d0 + jd] = dv[jd];
    }
    __syncthreads();
    for (int idx = t; idx < 8 * 48; idx += 256) {
        int pp = idx / 48, o4 = idx % 48;
        *(float4*)&dtout[((size_t)b * NN + n0 + pp) * DI + o4 * 4] = *(const float4*)&xcv[pp][o4 * 4];
    }
}

// ------- E: scan phase 1 — lane owns 8 states of one d; direct coalesced loads -------
__launch_bounds__(256)
__global__ void k_scan1(const float* __restrict__ aexp, const float* __restrict__ dt,
                        const float* __restrict__ xcv, const float* __restrict__ bm,
                        float* __restrict__ ca, float* __restrict__ cbv) {
    int t = threadIdx.x, w = t >> 6, l = t & 63;
    int T = blockIdx.x * 4 + w;                 // 1920 wave-tasks
    int b = T / (KCH * 6), rem = T % (KCH * 6);
    int kc = rem / 6, dg = rem % 6;
    int dl = l & 31, sh = l >> 5;
    int d = dg * 32 + dl;
    float a[8];
    {
        const float4* a4 = (const float4*)&aexp[d * DS + sh * 8];
        float4 a0 = a4[0], a1 = a4[1];
        a[0]=a0.x; a[1]=a0.y; a[2]=a0.z; a[3]=a0.w;
        a[4]=a1.x; a[5]=a1.y; a[6]=a1.z; a[7]=a1.w;
    }
    size_t nbase = (size_t)b * NN + kc * LCH;
    float ap[8], hb[8];
    #pragma unroll
    for (int j = 0; j < 8; ++j) { ap[j] = 1.f; hb[j] = 0.f; }
    for (int i = 0; i < LCH; ++i) {
        size_t g = (nbase + i) * DI + d;
        float dtv = dt[g];
        float xv  = xcv[g];
        const float4* b4 = (const float4*)&bm[(nbase + i) * DS + sh * 8];
        float4 b0 = b4[0], b1 = b4[1];
        float bmv[8] = {b0.x,b0.y,b0.z,b0.w,b1.x,b1.y,b1.z,b1.w};
        float bx_ = dtv * xv;
        #pragma unroll
        for (int j = 0; j < 8; ++j) {
            float dA = __expf(dtv * a[j]);
            ap[j] *= dA;
            hb[j] = fmaf(dA, hb[j], bx_ * bmv[j]);
        }
    }
    size_t cidx = ((size_t)(b * KCH + kc) * DI + d) * DS + sh * 8;
    *(float4*)&ca[cidx]      = make_float4(ap[0],ap[1],ap[2],ap[3]);
    *(float4*)&ca[cidx + 4]  = make_float4(ap[4],ap[5],ap[6],ap[7]);
    *(float4*)&cbv[cidx]     = make_float4(hb[0],hb[1],hb[2],hb[3]);
    *(float4*)&cbv[cidx + 4] = make_float4(hb[4],hb[5],hb[6],hb[7]);
}

// ------- F: scan phase 2 — sequential over chunks (hs aliases ca: no restrict) -------
__global__ void k_scan2(const float* ca, const float* cbv, float* hs) {
    int tid = blockIdx.x * 64 + threadIdx.x; // 6144 total
    int b = tid / (DI * DS), ds_ = tid % (DI * DS);
    float h = 0.f;
    for (int kc = 0; kc < KCH; ++kc) {
        size_t idx = (size_t)(b * KCH + kc) * (DI * DS) + ds_;
        float av = ca[idx];
        float bv2 = cbv[idx];
        hs[idx] = h;
        h = fmaf(av, h, bv2);
    }
}

// ------- G: scan phase 3 — replay + y + gate; 8 states/lane, 1 shfl/step -------
__launch_bounds__(256)
__global__ void k_scan3(const float* __restrict__ aexp, const float* __restrict__ Dp,
                        const float* __restrict__ dt, const float* __restrict__ xcv,
                        const float* __restrict__ bm, const float* __restrict__ cm,
                        const float* __restrict__ zin, const float* hs,
                        float* __restrict__ yout) {
    int t = threadIdx.x, w = t >> 6, l = t & 63;
    int T = blockIdx.x * 4 + w;
    int b = T / (KCH * 6), rem = T % (KCH * 6);
    int kc = rem / 6, dg = rem % 6;
    int dl = l & 31, sh = l >> 5;
    int d = dg * 32 + dl;
    float a[8];
    {
        const float4* a4 = (const float4*)&aexp[d * DS + sh * 8];
        float4 a0 = a4[0], a1 = a4[1];
        a[0]=a0.x; a[1]=a0.y; a[2]=a0.z; a[3]=a0.w;
        a[4]=a1.x; a[5]=a1.y; a[6]=a1.z; a[7]=a1.w;
    }
    float dpar = Dp[d];
    size_t nbase = (size_t)b * NN + kc * LCH;
    size_t cidx = ((size_t)(b * KCH + kc) * DI + d) * DS + sh * 8;
    float h[8];
    {
        float4 h0 = *(const float4*)&hs[cidx];
        float4 h1 = *(const float4*)&hs[cidx + 4];
        h[0]=h0.x; h[1]=h0.y; h[2]=h0.z; h[3]=h0.w;
        h[4]=h1.x; h[5]=h1.y; h[6]=h1.z; h[7]=h1.w;
    }
    for (int i = 0; i < LCH; ++i) {
        size_t g = (nbase + i) * DI + d;
        float dtv = dt[g];
        float xv  = xcv[g];
        float zv  = zin[g];
        size_t sb = (nbase + i) * DS + sh * 8;
        const float4* b4 = (const float4*)&bm[sb];
        const float4* c4p = (const float4*)&cm[sb];
        float4 b0 = b4[0], b1 = b4[1];
        float4 c0 = c4p[0], c1 = c4p[1];
        float bmv[8] = {b0.x,b0.y,b0.z,b0.w,b1.x,b1.y,b1.z,b1.w};
        float cmv[8] = {c0.x,c0.y,c0.z,c0.w,c1.x,c1.y,c1.z,c1.w};
        float bx_ = dtv * xv;
        float py = 0.f;
        #pragma unroll
        for (int j = 0; j < 8; ++j) {
            float dA = __expf(dtv * a[j]);
            h[j] = fmaf(dA, h[j], bx_ * bmv[j]);
            py = fmaf(h[j], cmv[j], py);
        }
        py += __shfl_xor(py, 32);
        if (l < 32) {
            float y = py + dpar * xv;
            y *= zv / (1.f + __expf(-zv));
            yout[g] = y;
        }
    }
}

// ------- H: out_proj (192 -> 96), row-major LDS, 8pos x 4out x 4 K-split -------
__launch_bounds__(256, 2)
__global__ void k_outproj(const float* __restrict__ ow, const float* __restrict__ yin,
                          float* __restrict__ yp) {
    __shared__ float wsm[32][196];             // 25.1 KB: W rows [g*32, g*32+32)
    __shared__ float yt[64][196];              // 50.2 KB
    int b = blockIdx.z, g = blockIdx.y, n0 = blockIdx.x * 64, t = threadIdx.x;

    for (int i = t; i < 32 * 48; i += 256) {
        int r = i / 48, c4 = i % 48;
        *(float4*)&wsm[r][c4 * 4] = *(const float4*)(ow + (size_t)(g * 32 + r) * DI + c4 * 4);
    }
    for (int i = t; i < 64 * 48; i += 256) {
        int p = i / 48, c4 = i % 48;
        *(float4*)&yt[p][c4 * 4] = *(const float4*)(yin + ((size_t)b * NN + n0 + p) * DI + c4 * 4);
    }
    __syncthreads();

    int l = t & 63, w = t >> 6;
    int oi = l & 7;             // 4 outs: oi*4..oi*4+3
    int kq = (l >> 3) & 3;      // K quarter (48 chans)
    int pi = w * 2 + (l >> 5);  // 8 pos: pi*8..pi*8+7
    float acc[4][8];
    #pragma unroll
    for (int j = 0; j < 4; ++j)
        #pragma unroll
        for (int pp = 0; pp < 8; ++pp) acc[j][pp] = 0.f;

    for (int c4 = 0; c4 < 12; ++c4) {
        int cg = kq * 12 + c4;
        float4 b0 = *(const float4*)&wsm[oi * 4 + 0][cg * 4];
        float4 b1 = *(const float4*)&wsm[oi * 4 + 1][cg * 4];
        float4 b2 = *(const float4*)&wsm[oi * 4 + 2][cg * 4];
        float4 b3 = *(const float4*)&wsm[oi * 4 + 3][cg * 4];
        #pragma unroll
        for (int pp = 0; pp < 8; ++pp) {
            float4 a = *(const float4*)&yt[pi * 8 + pp][cg * 4];
            acc[0][pp] = fmaf(a.x, b0.x, fmaf(a.y, b0.y, fmaf(a.z, b0.z, fmaf(a.w, b0.w, acc[0][pp]))));
            acc[1][pp] = fmaf(a.x, b1.x, fmaf(a.y, b1.y, fmaf(a.z, b1.z, fmaf(a.w, b1.w, acc[1][pp]))));
            acc[2][pp] = fmaf(a.x, b2.x, fmaf(a.y, b2.y, fmaf(a.z, b2.z, fmaf(a.w, b2.w, acc[2][pp]))));
            acc[3][pp] = fmaf(a.x, b3.x, fmaf(a.y, b3.y, fmaf(a.z, b3.z, fmaf(a.w, b3.w, acc[3][pp]))));
        }
    }
    // reduce over kq (lane bits 3,4)
    #pragma unroll
    for (int j = 0; j < 4; ++j)
        #pragma unroll
        for (int pp = 0; pp < 8; ++pp) {
            acc[j][pp] += __shfl_xor(acc[j][pp], 8);
            acc[j][pp] += __shfl_xor(acc[j][pp], 16);
        }
    if (kq == 0) {
        #pragma unroll
        for (int pp = 0; pp < 8; ++pp) {
            float4 v = make_float4(acc[0][pp], acc[1][pp], acc[2][pp], acc[3][pp]);
            *(float4*)&yp[((size_t)b * NN + n0 + pi * 8 + pp) * NC + g * 32 + oi * 4] = v;
        }
    }
}

// ---------------- I: gather rows by rank + transpose + coalesced final write ----------------
__launch_bounds__(256)
__global__ void k_final(const float* __restrict__ yp, const int* __restrict__ rank,
                        float* __restrict__ out) {
    __shared__ float ft[64][97];
    __shared__ int rk[64];
    int b = blockIdx.y, i0 = blockIdx.x * 64, t = threadIdx.x;
    if (t < 64) rk[t] = rank[i0 + t];
    __syncthreads();
    for (int idx = t; idx < 64 * 24; idx += 256) {
        int ii = idx / 24, j = idx % 24;
        float4 v = *(const float4*)&yp[((size_t)b * NN + rk[ii]) * NC + j * 4];
        ft[ii][j * 4 + 0] = v.x; ft[ii][j * 4 + 1] = v.y;
        ft[ii][j * 4 + 2] = v.z; ft[ii][j * 4 + 3] = v.w;
    }
    __syncthreads();
    for (int idx = t; idx < 96 * 64; idx += 256) {
        int c = idx >> 6, ii = idx & 63;
        out[((size_t)b * NC + c) * NN + i0 + ii] = ft[ii][c];
    }
}

extern "C" void kernel_launch(void* const* d_in, const int* in_sizes, int n_in,
                              void* d_out, int out_size, void* d_ws, size_t ws_size,
                              hipStream_t stream) {
    const float* x    = (const float*)d_in[0];
    const float* pv   = (const float*)d_in[1];
    const float* nw   = (const float*)d_in[2];
    const float* nbp  = (const float*)d_in[3];
    const float* win  = (const float*)d_in[4];
    const float* cw   = (const float*)d_in[5];
    const float* cb   = (const float*)d_in[6];
    const float* xpw  = (const float*)d_in[7];
    const float* dpw  = (const float*)d_in[8];
    const float* dpb  = (const float*)d_in[9];
    const float* alog = (const float*)d_in[10];
    const float* Dp   = (const float*)d_in[11];
    const float* ow   = (const float*)d_in[12];
    float* out = (float*)d_out;
    float* ws  = (float*)d_ws;

    float* keys = ws + OFF_KEYS;
    int*   rank = (int*)ws + OFF_RANK;
    float* aexp = ws + OFF_AEXP;
    float* xc   = ws + OFF_XC;
    float* z    = ws + OFF_Z;
    float* xcv  = ws + OFF_XCV;
    float* dt   = ws + OFF_DT;
    float* bmb  = ws + OFF_BM;
    float* cmb  = ws + OFF_CM;
    float* ca   = ws + OFF_CA;
    float* cbv  = ws + OFF_CB;
    float* hs   = ws + OFF_CA;  // alias: in-place with ca (scan2 reads ca[idx] before writing hs[idx])
    float* xn   = ws + OFF_CA;  // alias: ca/cb not yet live (scan1 runs later)
    float* y    = ws + OFF_XC;  // alias: xc dead after conv stage
    float* yp   = ws + OFF_DT;  // alias: dt dead after scan3

    k_keys<<<(NN + DI * DS + 255) / 256, 256, 0, stream>>>(pv, alog, keys, aexp, rank);
    k_rank<<<dim3(32, 8), 256, 0, stream>>>(keys, rank);
    k_ln<<<dim3(125, 2), 256, 0, stream>>>(x, nw, nbp, rank, xn);
    k_inproj<<<dim3(125, 8, 2), 256, 0, stream>>>(xn, win, xc, z);
    k_conv_xdt<<<dim3(1000, 2), 256, 0, stream>>>(cw, cb, xpw, dpw, dpb, xc, xcv, dt, bmb, cmb);
    k_scan1<<<(NB * KCH * 6) / 4, 256, 0, stream>>>(aexp, dt, xcv, bmb, ca, cbv);
    k_scan2<<<96, 64, 0, stream>>>(ca, cbv, hs);
    k_scan3<<<(NB * KCH * 6) / 4, 256, 0, stream>>>(aexp, Dp, dt, xcv, bmb, cmb, z, hs, y);
    k_outproj<<<dim3(125, 3, 2), 256, 0, stream>>>(ow, y, yp);
    k_final<<<dim3(125, 2), 256, 0, stream>>>(yp, rank, out);
}